// Round 1
// baseline (499.567 us; speedup 1.0000x reference)
//
#include <hip/hip_runtime.h>
#include <math.h>

// NeighborlistVerletNsq: N=4096 particles, P = N(N-1)/2 pairs.
// Outputs (flattened float32, in return order):
//   [0      , 4P ) pairs   [2,2P] row-major: row0 = concat(i,j), row1 = concat(j,i)
//   [4P     , 6P ) d_full  [2P,1]: concat(d_m, d_m)
//   [6P     , 12P) r_full  [2P,3] row-major: concat(r_m, -r_m)
//   [12P    , 14P) mask    [2P]: concat(mask, mask) as 0/1
//
// Numerics match numpy fp32 exactly:
//   remainder(t, L) = fmodf(t, L) (+L if negative)   [fmod is exact]
//   d = sqrtf(((x*x)+(y*y))+(z*z))  with no fma contraction (__fmul_rn/__fadd_rn)

#define CUTOFF_F 0.5f

__device__ __forceinline__ float pbc_wrap(float r, float L, float h) {
    float t = __fadd_rn(r, h);        // r + half
    float m = fmodf(t, L);            // exact, sign of dividend
    if (m < 0.0f) m = __fadd_rn(m, L); // numpy remainder sign fixup (L > 0)
    return __fsub_rn(m, h);           // - half
}

__global__ __launch_bounds__(256)
void nl_nsq_kernel(const float* __restrict__ pos,
                   const float* __restrict__ box,
                   const int*   __restrict__ ip,
                   const int*   __restrict__ jp,
                   float*       __restrict__ out,
                   long long P) {
    long long p = (long long)blockIdx.x * blockDim.x + threadIdx.x;
    if (p >= P) return;

    const int i = ip[p];
    const int j = jp[p];

    const float Lx = box[0], Ly = box[4], Lz = box[8];
    const float hx = Lx * 0.5f, hy = Ly * 0.5f, hz = Lz * 0.5f;

    float rx = __fsub_rn(pos[3 * i + 0], pos[3 * j + 0]);
    float ry = __fsub_rn(pos[3 * i + 1], pos[3 * j + 1]);
    float rz = __fsub_rn(pos[3 * i + 2], pos[3 * j + 2]);

    rx = pbc_wrap(rx, Lx, hx);
    ry = pbc_wrap(ry, Ly, hy);
    rz = pbc_wrap(rz, Lz, hz);

    // no-fma norm: ((x*x + y*y) + z*z), each op rounded fp32
    float d2 = __fadd_rn(__fadd_rn(__fmul_rn(rx, rx), __fmul_rn(ry, ry)),
                         __fmul_rn(rz, rz));
    float d = sqrtf(d2);

    const bool keep = (d <= CUTOFF_F);
    const float dm  = keep ? d  : 0.0f;
    const float mx  = keep ? rx : 0.0f;
    const float my  = keep ? ry : 0.0f;
    const float mz  = keep ? rz : 0.0f;
    const float mk  = keep ? 1.0f : 0.0f;

    const float fi = (float)i;
    const float fj = (float)j;

    // pairs [2, 2P]
    out[p]          = fi;
    out[P + p]      = fj;
    out[2 * P + p]  = fj;
    out[3 * P + p]  = fi;
    // d_full [2P]
    out[4 * P + p]  = dm;
    out[5 * P + p]  = dm;
    // r_full [2P, 3]
    {
        long long b0 = 6 * P + 3 * p;
        out[b0 + 0] = mx;
        out[b0 + 1] = my;
        out[b0 + 2] = mz;
        long long b1 = 6 * P + 3 * (P + p);
        out[b1 + 0] = -mx;
        out[b1 + 1] = -my;
        out[b1 + 2] = -mz;
    }
    // mask_full [2P]
    out[12 * P + p] = mk;
    out[13 * P + p] = mk;
}

extern "C" void kernel_launch(void* const* d_in, const int* in_sizes, int n_in,
                              void* d_out, int out_size, void* d_ws, size_t ws_size,
                              hipStream_t stream) {
    const float* pos = (const float*)d_in[0];  // [N,3]
    const float* box = (const float*)d_in[1];  // [3,3]
    const int*   ip  = (const int*)d_in[2];    // [P]
    const int*   jp  = (const int*)d_in[3];    // [P]
    float*       out = (float*)d_out;

    const long long P = (long long)in_sizes[2];

    const int block = 256;
    const long long grid = (P + block - 1) / block;
    nl_nsq_kernel<<<(dim3)(unsigned)grid, block, 0, stream>>>(pos, box, ip, jp, out, P);
}